// Round 6
// baseline (936.176 us; speedup 1.0000x reference)
//
#include <hip/hip_runtime.h>
#include <math.h>

#define NN 100000
#define NE 1600000
#define NG 64
#define FF 50
#define NL 3
#define NBUCK ((NN + 255) / 256)   // 391

typedef short bf16x8 __attribute__((ext_vector_type(8)));
typedef float f32x4 __attribute__((ext_vector_type(4)));

__device__ __forceinline__ short f2bf(float f) {
  return __builtin_bit_cast(short, (__bf16)f);
}
__device__ __forceinline__ float bf2f(short s) {
  unsigned int u = ((unsigned int)(unsigned short)s) << 16;
  return __builtin_bit_cast(float, u);
}
__device__ __forceinline__ float2 unpk2(unsigned u) {
  float2 v;
  v.x = __builtin_bit_cast(float, u << 16);
  v.y = __builtin_bit_cast(float, u & 0xFFFF0000u);
  return v;
}
__device__ __forceinline__ unsigned pk2(float2 v) {
  return (unsigned)(unsigned short)f2bf(v.x) | ((unsigned)(unsigned short)f2bf(v.y) << 16);
}

// ---------------- degree ----------------
__global__ void k_deg(const int* __restrict__ dst, int* __restrict__ deg) {
  int e = blockIdx.x * blockDim.x + threadIdx.x;
  if (e < NE) atomicAdd(&deg[dst[e]], 1);
}

// ---------------- prefix scan ----------------
__global__ void k_scan1(const int* __restrict__ deg, int* __restrict__ off, int* __restrict__ parts) {
  __shared__ int sm[1024];
  int i = blockIdx.x * 1024 + threadIdx.x;
  int v = (i < NN) ? deg[i] : 0;
  sm[threadIdx.x] = v;
  __syncthreads();
  for (int ofs = 1; ofs < 1024; ofs <<= 1) {
    int t = (threadIdx.x >= ofs) ? sm[threadIdx.x - ofs] : 0;
    __syncthreads();
    sm[threadIdx.x] += t;
    __syncthreads();
  }
  if (i < NN) off[i] = sm[threadIdx.x] - v;
  if (threadIdx.x == 1023) parts[blockIdx.x] = sm[1023];
}

__global__ void k_scan2(int* __restrict__ parts, int nb) {
  __shared__ int sm[128];
  int v = (threadIdx.x < nb) ? parts[threadIdx.x] : 0;
  sm[threadIdx.x] = v;
  __syncthreads();
  for (int ofs = 1; ofs < 128; ofs <<= 1) {
    int t = (threadIdx.x >= ofs) ? sm[threadIdx.x - ofs] : 0;
    __syncthreads();
    sm[threadIdx.x] += t;
    __syncthreads();
  }
  if (threadIdx.x < nb) parts[threadIdx.x] = sm[threadIdx.x] - v;
}

__global__ void k_scan3(int* __restrict__ off, const int* __restrict__ parts, int* __restrict__ bcur) {
  int i = blockIdx.x * 256 + threadIdx.x;
  if (i < NN) {
    int v = off[i] + parts[i >> 10];
    off[i] = v;
    if ((i & 255) == 0) bcur[i >> 8] = v;
  }
  if (i == 0) off[NN] = NE;
}

// ---------------- node init ----------------
__global__ void k_nodeinit(const int* __restrict__ deg, float* __restrict__ dinv,
                           float* __restrict__ lgc, float* __restrict__ scal) {
  int i = blockIdx.x * 256 + threadIdx.x;
  float lp = 0.f;
  if (i < NN) {
    int d = deg[i];
    dinv[i] = rsqrtf((float)(d + 1));
    int dc = d > 1 ? d : 1;
    lgc[i] = log1pf((float)dc);
    lp = log1pf((float)d);
  }
  for (int o = 32; o > 0; o >>= 1) lp += __shfl_down(lp, o);
  __shared__ float red[4];
  int lane = threadIdx.x & 63, w = threadIdx.x >> 6;
  if (lane == 0) red[w] = lp;
  __syncthreads();
  if (threadIdx.x == 0) atomicAdd(scal, red[0] + red[1] + red[2] + red[3]);
}

// ---------------- phase A: bin edges ----------------
__global__ __launch_bounds__(256) void k_bucket(const int* __restrict__ src, const int* __restrict__ dst,
                                                int* __restrict__ bcur, unsigned* __restrict__ tmp) {
  __shared__ int hist[NBUCK];
  __shared__ int base[NBUCK];
  int t = threadIdx.x;
  for (int i = t; i < NBUCK; i += 256) hist[i] = 0;
  __syncthreads();
  int e0 = blockIdx.x * 4096;
  int myb[16], myrank[16];
  unsigned mypack[16];
#pragma unroll
  for (int i = 0; i < 16; ++i) {
    int e = e0 + i * 256 + t;
    if (e < NE) {
      int s = src[e], d = dst[e];
      int b = d >> 8;
      myb[i] = b;
      mypack[i] = ((unsigned)(d & 255) << 17) | (unsigned)s;
      myrank[i] = atomicAdd(&hist[b], 1);
    } else myb[i] = -1;
  }
  __syncthreads();
  for (int i = t; i < NBUCK; i += 256)
    base[i] = hist[i] ? atomicAdd(&bcur[i], hist[i]) : 0;
  __syncthreads();
#pragma unroll
  for (int i = 0; i < 16; ++i)
    if (myb[i] >= 0) tmp[base[myb[i]] + myrank[i]] = mypack[i];
}

// ---------------- phase B: bucket -> CSR ----------------
__global__ __launch_bounds__(256) void k_bsort(const int* __restrict__ off, const unsigned* __restrict__ tmp,
                                               int* __restrict__ ssrc) {
  int b = blockIdx.x;
  int n0 = b * 256;
  int nEnd = n0 + 256 < NN ? n0 + 256 : NN;
  __shared__ int cnt[256];
  __shared__ int nb[256];
  int t = threadIdx.x;
  cnt[t] = 0;
  if (n0 + t < nEnd) nb[t] = off[n0 + t];
  __syncthreads();
  int lo = off[n0], hiE = off[nEnd];
  for (int e = lo + t; e < hiE; e += 256) {
    unsigned p = tmp[e];
    int dloc = p >> 17;
    int s = (int)(p & 0x1FFFFu);
    int pos = nb[dloc] + atomicAdd(&cnt[dloc], 1);
    ssrc[pos] = s;
  }
}

// ---------------- fuse post_W @ lin_W ----------------
__global__ void k_fusew(const float* __restrict__ postW, const float* __restrict__ postb,
                        const float* __restrict__ linW, const float* __restrict__ linb,
                        float* __restrict__ A, float* __restrict__ bias2) {
  int wid = (blockIdx.x * blockDim.x + threadIdx.x) >> 6;
  int f = threadIdx.x & 63;
  if (wid >= 3 * 651) return;
  int l = wid / 651, r = wid % 651;
  int fc = f < FF ? f : FF - 1;
  const float* lw = linW + l * FF * FF;
  float acc = 0.f;
  if (r < 650) {
    const float* pw = postW + (l * 650 + r) * FF;
    for (int j = 0; j < FF; ++j) acc += pw[j] * lw[j * FF + fc];
    if (f < FF) A[(l * 650 + r) * FF + f] = acc;
  } else {
    const float* pb = postb + l * FF;
    for (int j = 0; j < FF; ++j) acc += pb[j] * lw[j * FF + fc];
    if (f < FF) bias2[l * 64 + f] = acc + linb[l * FF + f];
  }
}

// ---------------- pack A ----------------
__global__ void k_packA(const float* __restrict__ Af, short* __restrict__ Abt) {
  int t = blockIdx.x * 256 + threadIdx.x;
  if (t >= 3 * 13 * 64 * 64) return;
  int kk = t & 63;
  int f = (t >> 6) & 63;
  int lc = t >> 12;
  int c = lc % 13;
  int l = lc / 13;
  float v = 0.f;
  if (kk < FF && f < FF) v = Af[((size_t)(l * 650 + c * FF + kk)) * FF + f];
  Abt[t] = f2bf(v);
}

// ---------------- pack pre_W ----------------
__global__ void k_packP(const float* __restrict__ preW, short* __restrict__ Pbt) {
  int t = blockIdx.x * 256 + threadIdx.x;
  if (t >= NL * 2 * 64 * 64) return;
  int kk = t & 63;
  int f = (t >> 6) & 63;
  int ls = t >> 12;
  int s = ls & 1, l = ls >> 1;
  float v = 0.f;
  if (kk < FF && f < FF) v = preW[(size_t)(l * 100 + s * FF + kk) * FF + f];
  Pbt[t] = f2bf(v);
}

// ---------------- GCN pre ----------------
__global__ void k_gcnpre(const float* __restrict__ x, const float* __restrict__ Wg,
                         const float* __restrict__ dinv, short* __restrict__ pb) {
  int t = blockIdx.x * 256 + threadIdx.x;
  int n = t >> 6, f = t & 63;
  if (n >= NN) return;
  float v = 0.f;
  if (f < FF) v = (x[2 * n] * Wg[f] + x[2 * n + 1] * Wg[FF + f]) * dinv[n];
  pb[n * 64 + f] = f2bf(v);
}

// ---------------- GCN aggregation (packed: 2 edges x 2 features) ----------------
__global__ void k_gcnagg(const short* __restrict__ pb, const int* __restrict__ off,
                         const int* __restrict__ ssrc, const float* __restrict__ dinv,
                         const float* __restrict__ bg, float* __restrict__ h) {
  int wid = (blockIdx.x * blockDim.x + threadIdx.x) >> 6;
  int lane = threadIdx.x & 63;
  if (wid >= NN) return;
  int n = wid;
  int p = lane & 31;
  int hf = lane >> 5;
  float2 acc;
  {
    float2 sv = unpk2(*(const unsigned*)(pb + n * 64 + 2 * p));
    acc.x = hf ? 0.f : sv.x;
    acc.y = hf ? 0.f : sv.y;
  }
  int lo = off[n], hi = off[n + 1];
  for (int base = lo; base < hi; base += 64) {
    int rem = hi - base;
    int cnt = rem > 64 ? 64 : rem;
    int sidx = (base + lane < hi) ? ssrc[base + lane] : 0;
    int pairs = cnt >> 1;
    int j = 0;
    for (; j + 4 <= pairs; j += 4) {
#pragma unroll
      for (int i = 0; i < 4; ++i) {
        int s = __shfl(sidx, 2 * (j + i) + hf);
        float2 v = unpk2(*(const unsigned*)(pb + s * 64 + 2 * p));
        acc.x += v.x; acc.y += v.y;
      }
    }
    for (; j < pairs; ++j) {
      int s = __shfl(sidx, 2 * j + hf);
      float2 v = unpk2(*(const unsigned*)(pb + s * 64 + 2 * p));
      acc.x += v.x; acc.y += v.y;
    }
    if (cnt & 1) {
      int s = __shfl(sidx, cnt - 1);
      float2 v = unpk2(*(const unsigned*)(pb + s * 64 + 2 * p));
      if (hf == 0) { acc.x += v.x; acc.y += v.y; }
    }
  }
  acc.x += __shfl_xor(acc.x, 32);
  acc.y += __shfl_xor(acc.y, 32);
  if (lane < 32 && p < 25) {
    float dv = dinv[n];
    float2 bgp = *(const float2*)(bg + 2 * p);
    *(float2*)(h + n * FF + 2 * p) = make_float2(dv * acc.x + bgp.x, dv * acc.y + bgp.y);
  }
}

// ---------------- PNA pre (MFMA, barrier-free) ----------------
__global__ __launch_bounds__(256) void k_preM(const float* __restrict__ hin, const float2* __restrict__ ab,
                                              const short* __restrict__ Pbt, const float* __restrict__ preb,
                                              float* __restrict__ cb, short* __restrict__ bbh, int l) {
  __shared__ short Xs[64][72];
  int tid = threadIdx.x;
  int w = tid >> 6, lane = tid & 63;
  int q = lane >> 4, m16 = lane & 15;
  int n0 = blockIdx.x * 64 + w * 16;

  int nl = lane >> 2, ks = lane & 3;
  int n = n0 + nl;
  bool nv = n < NN;
  int row = w * 16 + nl;
  {
    const float* hrow = hin + (size_t)(nv ? n : 0) * FF;
    short tmp[16] __attribute__((aligned(16)));
#pragma unroll
    for (int j = 0; j < 16; j += 2) {
      int kk = ks * 16 + j;
      float2 v = {0.f, 0.f};
      if (nv && kk < FF) v = *(const float2*)(hrow + kk);
      if (ab) {
        float2 p0 = ab[kk], p1 = ab[kk + 1];
        v.x = fmaxf(fmaf(v.x, p0.x, p0.y), 0.f);
        v.y = fmaxf(fmaf(v.y, p1.x, p1.y), 0.f);
      }
      tmp[j] = f2bf(v.x); tmp[j + 1] = f2bf(v.y);
    }
    *(float4*)&Xs[row][ks * 16] = *(const float4*)&tmp[0];
    *(float4*)&Xs[row][ks * 16 + 8] = *(const float4*)&tmp[8];
  }
  const short* P0 = Pbt + l * 8192;
  f32x4 aT[4], aB2[4];
#pragma unroll
  for (int ft = 0; ft < 4; ++ft) {
    aT[ft] = (f32x4){0.f, 0.f, 0.f, 0.f};
    aB2[ft] = (f32x4){0.f, 0.f, 0.f, 0.f};
  }
#pragma unroll
  for (int hh = 0; hh < 2; ++hh) {
    bf16x8 a = *(const bf16x8*)&Xs[w * 16 + m16][hh * 32 + q * 8];
#pragma unroll
    for (int ft = 0; ft < 4; ++ft) {
      bf16x8 b0 = *(const bf16x8*)(P0 + ((ft * 16 + m16) << 6) + hh * 32 + q * 8);
      bf16x8 b1 = *(const bf16x8*)(P0 + 4096 + ((ft * 16 + m16) << 6) + hh * 32 + q * 8);
      aT[ft] = __builtin_amdgcn_mfma_f32_16x16x32_bf16(a, b0, aT[ft], 0, 0, 0);
      aB2[ft] = __builtin_amdgcn_mfma_f32_16x16x32_bf16(a, b1, aB2[ft], 0, 0, 0);
    }
  }
#pragma unroll
  for (int r = 0; r < 4; ++r) {
    int node = n0 + q * 4 + r;
    if (node >= NN) continue;
#pragma unroll
    for (int ft = 0; ft < 4; ++ft) {
      int col = ft * 16 + m16;
      if (col < FF) cb[node * FF + col] = aT[ft][r] + preb[l * FF + col];
      bbh[node * 64 + col] = f2bf(aB2[ft][r]);
    }
  }
}

// ---------------- PNA aggregation (packed: 2 edges x 2 features) ----------------
__global__ void k_agg(const short* __restrict__ bbh, const float* __restrict__ cb,
                      const int* __restrict__ off, const int* __restrict__ ssrc,
                      const float* __restrict__ lgc, const float* __restrict__ scal,
                      short* __restrict__ agb, float* __restrict__ ampatt) {
  int wid = (blockIdx.x * blockDim.x + threadIdx.x) >> 6;
  int lane = threadIdx.x & 63;
  if (wid >= NN) return;
  int n = wid;
  int p = lane & 31;
  int hf = lane >> 5;
  float2 S = {0.f, 0.f}, S2 = {0.f, 0.f};
  float2 MN = {INFINITY, INFINITY}, MX = {-INFINITY, -INFINITY};
  int lo = off[n], hi = off[n + 1];
  for (int base = lo; base < hi; base += 64) {
    int rem = hi - base;
    int cnt = rem > 64 ? 64 : rem;
    int sidx = (base + lane < hi) ? ssrc[base + lane] : 0;
    int pairs = cnt >> 1;
    int j = 0;
    for (; j + 4 <= pairs; j += 4) {
#pragma unroll
      for (int i = 0; i < 4; ++i) {
        int s = __shfl(sidx, 2 * (j + i) + hf);
        float2 v = unpk2(*(const unsigned*)(bbh + s * 64 + 2 * p));
        S.x += v.x; S.y += v.y;
        S2.x = fmaf(v.x, v.x, S2.x); S2.y = fmaf(v.y, v.y, S2.y);
        MN.x = fminf(MN.x, v.x); MN.y = fminf(MN.y, v.y);
        MX.x = fmaxf(MX.x, v.x); MX.y = fmaxf(MX.y, v.y);
      }
    }
    for (; j < pairs; ++j) {
      int s = __shfl(sidx, 2 * j + hf);
      float2 v = unpk2(*(const unsigned*)(bbh + s * 64 + 2 * p));
      S.x += v.x; S.y += v.y;
      S2.x = fmaf(v.x, v.x, S2.x); S2.y = fmaf(v.y, v.y, S2.y);
      MN.x = fminf(MN.x, v.x); MN.y = fminf(MN.y, v.y);
      MX.x = fmaxf(MX.x, v.x); MX.y = fmaxf(MX.y, v.y);
    }
    if (cnt & 1) {
      int s = __shfl(sidx, cnt - 1);
      float2 v = unpk2(*(const unsigned*)(bbh + s * 64 + 2 * p));
      if (hf == 0) {
        S.x += v.x; S.y += v.y;
        S2.x = fmaf(v.x, v.x, S2.x); S2.y = fmaf(v.y, v.y, S2.y);
        MN.x = fminf(MN.x, v.x); MN.y = fminf(MN.y, v.y);
        MX.x = fmaxf(MX.x, v.x); MX.y = fmaxf(MX.y, v.y);
      }
    }
  }
  S.x += __shfl_xor(S.x, 32);   S.y += __shfl_xor(S.y, 32);
  S2.x += __shfl_xor(S2.x, 32); S2.y += __shfl_xor(S2.y, 32);
  MN.x = fminf(MN.x, __shfl_xor(MN.x, 32)); MN.y = fminf(MN.y, __shfl_xor(MN.y, 32));
  MX.x = fmaxf(MX.x, __shfl_xor(MX.x, 32)); MX.y = fmaxf(MX.y, __shfl_xor(MX.y, 32));
  int d = hi - lo;
  bool valid = p < 25;
  float2 mean, mnv, mxv, stdv;
  if (d > 0) {
    float inv = 1.f / (float)d;
    float2 m = make_float2(S.x * inv, S.y * inv);
    float vx = S2.x * inv - m.x * m.x; vx = vx > 0.f ? vx : 0.f;
    float vy = S2.y * inv - m.y * m.y; vy = vy > 0.f ? vy : 0.f;
    stdv = make_float2(sqrtf(vx + 1e-5f), sqrtf(vy + 1e-5f));
    float2 c = valid ? *(const float2*)(cb + n * FF + 2 * p) : make_float2(0.f, 0.f);
    mean = make_float2(c.x + m.x, c.y + m.y);
    mnv = make_float2(c.x + MN.x, c.y + MN.y);
    mxv = make_float2(c.x + MX.x, c.y + MX.y);
  } else {
    mean = mnv = mxv = make_float2(0.f, 0.f);
    float sq = sqrtf(1e-5f);
    stdv = make_float2(sq, sq);
  }
  if (lane < 32) {
    unsigned* row32 = (unsigned*)(agb + (size_t)n * 256);
    row32[p]      = valid ? pk2(mean) : 0u;
    row32[32 + p] = valid ? pk2(mnv) : 0u;
    row32[64 + p] = valid ? pk2(mxv) : 0u;
    row32[96 + p] = valid ? pk2(stdv) : 0u;
  }
  if (lane == 0) {
    float avg = scal[0] * (1.f / NN);
    float lg = lgc[n];
    ampatt[2 * n] = lg / avg;
    ampatt[2 * n + 1] = avg / lg;
  }
}

// ---------------- post GEMM (bf16 MFMA, barrier-free, B from global) ----------------
__global__ __launch_bounds__(256, 3) void k_gemm(const float* __restrict__ h, const float2* __restrict__ ab,
                                                 const short* __restrict__ agb, const float* __restrict__ ampatt,
                                                 const short* __restrict__ Abt, const float* __restrict__ bias2,
                                                 float* __restrict__ out, float* __restrict__ bnsumR) {
  __shared__ short Xs[64][328];  // 656B row stride -> bank shift 4/row: 2-way (free)
  int tid = threadIdx.x;
  int w = tid >> 6, lane = tid & 63;
  int q = lane >> 4, m16 = lane & 15;
  int n0 = blockIdx.x * 64 + w * 16;

  // per-wave staging of its own 16 node rows
  int nl = lane >> 2, ks = lane & 3;
  int n = n0 + nl;
  bool nv = n < NN;
  int row = w * 16 + nl;
  const short* arow = agb + (size_t)(nv ? n : 0) * 256;
#pragma unroll
  for (int c = 1; c <= 4; ++c) {
    const float4* g = (const float4*)(arow + (c - 1) * 64 + ks * 16);
    float4 z = {0.f, 0.f, 0.f, 0.f};
    float4 v0 = nv ? g[0] : z;
    float4 v1 = nv ? g[1] : z;
    *(float4*)&Xs[row][c * 64 + ks * 16] = v0;
    *(float4*)&Xs[row][c * 64 + ks * 16 + 8] = v1;
  }
  {
    const float* hrow = h + (size_t)(nv ? n : 0) * FF;
    short tmp[16] __attribute__((aligned(16)));
#pragma unroll
    for (int j = 0; j < 16; j += 2) {
      int kk = ks * 16 + j;
      float2 v = {0.f, 0.f};
      if (nv && kk < FF) v = *(const float2*)(hrow + kk);
      if (ab) {
        float2 p0 = ab[kk], p1 = ab[kk + 1];
        v.x = fmaxf(fmaf(v.x, p0.x, p0.y), 0.f);
        v.y = fmaxf(fmaf(v.y, p1.x, p1.y), 0.f);
      }
      tmp[j] = f2bf(v.x); tmp[j + 1] = f2bf(v.y);
    }
    *(float4*)&Xs[row][ks * 16] = *(const float4*)&tmp[0];
    *(float4*)&Xs[row][ks * 16 + 8] = *(const float4*)&tmp[8];
  }
  // no __syncthreads: wave reads only its own rows (compiler inserts lgkmcnt waits)

  f32x4 acc[3][4];
#pragma unroll
  for (int s = 0; s < 3; ++s)
#pragma unroll
    for (int ft = 0; ft < 4; ++ft) acc[s][ft] = (f32x4){0.f, 0.f, 0.f, 0.f};

#pragma unroll
  for (int hh = 0; hh < 2; ++hh) {
    bf16x8 a = *(const bf16x8*)&Xs[w * 16 + m16][hh * 32 + q * 8];
#pragma unroll
    for (int ft = 0; ft < 4; ++ft) {
      bf16x8 b = *(const bf16x8*)(Abt + ((ft * 16 + m16) << 6) + hh * 32 + q * 8);
      acc[0][ft] = __builtin_amdgcn_mfma_f32_16x16x32_bf16(a, b, acc[0][ft], 0, 0, 0);
    }
  }
  for (int c = 1; c <= 4; ++c) {
#pragma unroll
    for (int hh = 0; hh < 2; ++hh) {
      bf16x8 a = *(const bf16x8*)&Xs[w * 16 + m16][c * 64 + hh * 32 + q * 8];
#pragma unroll
      for (int s = 0; s < 3; ++s) {
        const short* Bc = Abt + ((c + 4 * s) << 12);
#pragma unroll
        for (int ft = 0; ft < 4; ++ft) {
          bf16x8 b = *(const bf16x8*)(Bc + ((ft * 16 + m16) << 6) + hh * 32 + q * 8);
          acc[s][ft] = __builtin_amdgcn_mfma_f32_16x16x32_bf16(a, b, acc[s][ft], 0, 0, 0);
        }
      }
    }
  }
  float sacc[4] = {0.f, 0.f, 0.f, 0.f};
  float qacc[4] = {0.f, 0.f, 0.f, 0.f};
#pragma unroll
  for (int r = 0; r < 4; ++r) {
    int node = n0 + q * 4 + r;
    if (node >= NN) continue;
    float2 aa = *(const float2*)(ampatt + 2 * node);
#pragma unroll
    for (int ft = 0; ft < 4; ++ft) {
      int col = ft * 16 + m16;
      if (col >= FF) continue;
      float val = acc[0][ft][r] + aa.x * acc[1][ft][r] + aa.y * acc[2][ft][r] + bias2[col];
      out[node * FF + col] = val;
      sacc[ft] += val;
      qacc[ft] = fmaf(val, val, qacc[ft]);
    }
  }
#pragma unroll
  for (int ft = 0; ft < 4; ++ft) {
    sacc[ft] += __shfl_xor(sacc[ft], 16);
    sacc[ft] += __shfl_xor(sacc[ft], 32);
    qacc[ft] += __shfl_xor(qacc[ft], 16);
    qacc[ft] += __shfl_xor(qacc[ft], 32);
  }
  if (lane < 16) {
    float* bl = bnsumR + (blockIdx.x & 7) * 128;
#pragma unroll
    for (int ft = 0; ft < 4; ++ft) {
      int col = ft * 16 + lane;
      if (col < FF) {
        atomicAdd(&bl[col], sacc[ft]);
        atomicAdd(&bl[64 + col], qacc[ft]);
      }
    }
  }
}

// ---------------- BN coeffs from 8 replicas ----------------
__global__ void k_bnab(const float* __restrict__ bnsumR, const float* __restrict__ gamma,
                       const float* __restrict__ beta, float2* __restrict__ ab, int l) {
  int f = threadIdx.x;
  float a = 0.f, b = 0.f;
  if (f < FF) {
    float s = 0.f, q = 0.f;
    for (int r = 0; r < 8; ++r) { s += bnsumR[r * 128 + f]; q += bnsumR[r * 128 + 64 + f]; }
    float mu = s * (1.f / NN);
    float vq = q * (1.f / NN) - mu * mu;
    float rs = rsqrtf((vq > 0.f ? vq : 0.f) + 1e-5f);
    a = rs * gamma[l * FF + f];
    b = beta[l * FF + f] - mu * a;
  }
  ab[f] = make_float2(a, b);
}

// ---------------- graph partial sums (fused BN+ReLU of last layer) ----------------
__global__ void k_gsum(const float* __restrict__ h, const float2* __restrict__ ab,
                       const int* __restrict__ batch, float* __restrict__ gsum) {
  int w = threadIdx.x >> 6, lane = threadIdx.x & 63;
  int fc = lane < FF ? lane : FF - 1;
  bool act = lane < FF;
  float2 p = ab[fc];
  int n0 = blockIdx.x * 256 + w * 64;
  if (n0 >= NN) return;
  int nEnd = n0 + 64 < NN ? n0 + 64 : NN;
  float acc = 0.f;
  int gcur = batch[n0];
  for (int n = n0; n < nEnd; ++n) {
    int g = batch[n];
    if (g != gcur) {
      if (act) atomicAdd(&gsum[gcur * 64 + lane], acc);
      acc = 0.f; gcur = g;
    }
    float v = h[n * FF + fc];
    acc += fmaxf(fmaf(v, p.x, p.y), 0.f);
  }
  if (act) atomicAdd(&gsum[gcur * 64 + lane], acc);
}

// ---------------- final MLP ----------------
__global__ void k_mlp(const float* __restrict__ gsum, const float* __restrict__ W1,
                      const float* __restrict__ b1, const float* __restrict__ W2,
                      const float* __restrict__ b2, float* __restrict__ out) {
  int g = threadIdx.x;
  if (g >= NG) return;
  float gv[FF];
#pragma unroll
  for (int f = 0; f < FF; ++f) gv[f] = gsum[g * 64 + f];
  float r = b2[0];
  for (int j = 0; j < 25; ++j) {
    float a = b1[j];
#pragma unroll
    for (int f = 0; f < FF; ++f) a = fmaf(gv[f], W1[f * 25 + j], a);
    r += fmaxf(a, 0.f) * W2[j];
  }
  out[g] = r;
}

extern "C" void kernel_launch(void* const* d_in, const int* in_sizes, int n_in,
                              void* d_out, int out_size, void* d_ws, size_t ws_size,
                              hipStream_t stream) {
  const float* x     = (const float*)d_in[0];
  const int*   ei    = (const int*)d_in[1];
  const int*   src   = ei;
  const int*   dst   = ei + NE;
  const int*   batch = (const int*)d_in[2];
  const float* Wg    = (const float*)d_in[3];
  const float* bg    = (const float*)d_in[4];
  const float* preW  = (const float*)d_in[5];
  const float* preb  = (const float*)d_in[6];
  const float* postW = (const float*)d_in[7];
  const float* postb = (const float*)d_in[8];
  const float* linW  = (const float*)d_in[9];
  const float* linb  = (const float*)d_in[10];
  const float* gamma = (const float*)d_in[11];
  const float* beta  = (const float*)d_in[12];
  const float* W1    = (const float*)d_in[13];
  const float* b1    = (const float*)d_in[14];
  const float* W2    = (const float*)d_in[15];
  const float* b2    = (const float*)d_in[16];
  float* out = (float*)d_out;

  char* W = (char*)d_ws;
  int*    deg    = (int*)(W + 0);            // 400384
  int*    off    = (int*)(W + 400384);       // 400896
  int*    bcur   = (int*)(W + 801280);       // 2048
  int*    parts  = (int*)(W + 803328);       // 4096
  float*  dinv   = (float*)(W + 807424);     // 400384
  float*  lgc    = (float*)(W + 1207808);    // 400384
  float*  scal   = (float*)(W + 1608192);    // 512
  float*  bnsum  = (float*)(W + 1608704);    // 12288 (3 layers x 8 reps x 128 f)
  float2* ab     = (float2*)(W + 1620992);   // 1536
  float*  Af     = (float*)(W + 1622528);    // 390144
  float*  bias2  = (float*)(W + 2012672);    // 1024
  short*  Abt    = (short*)(W + 2013696);    // 319488
  short*  Pbt    = (short*)(W + 2333184);    // 49152
  unsigned* tmp  = (unsigned*)(W + 2382336); // 6400000
  int*    ssrc   = (int*)(W + 8782336);      // 6400000
  float*  hA     = (float*)(W + 15182336);   // 20000256
  float*  hB     = (float*)(W + 35182592);   // 20000256
  float*  cb     = (float*)(W + 55182848);   // 20000256
  short*  bbh    = (short*)(W + 75183104);   // 12800256
  short*  agb    = (short*)(W + 87983360);   // 51200256
  float*  ampatt = (float*)(W + 139183616);  // 800256
  float*  gsum   = (float*)(W + 139983872);  // 16384

  hipMemsetAsync(deg, 0, 400384, stream);
  hipMemsetAsync(scal, 0, 12800, stream);   // scal + bnsum
  hipMemsetAsync(gsum, 0, 16384, stream);

  k_deg<<<(NE + 255) / 256, 256, 0, stream>>>(dst, deg);
  k_scan1<<<98, 1024, 0, stream>>>(deg, off, parts);
  k_scan2<<<1, 128, 0, stream>>>(parts, 98);
  k_scan3<<<(NN + 255) / 256, 256, 0, stream>>>(off, parts, bcur);
  k_nodeinit<<<(NN + 255) / 256, 256, 0, stream>>>(deg, dinv, lgc, scal);
  k_bucket<<<(NE + 4095) / 4096, 256, 0, stream>>>(src, dst, bcur, tmp);
  k_bsort<<<NBUCK, 256, 0, stream>>>(off, tmp, ssrc);
  k_fusew<<<(3 * 651 + 3) / 4, 256, 0, stream>>>(postW, postb, linW, linb, Af, bias2);
  k_packA<<<(3 * 13 * 64 * 64 + 255) / 256, 256, 0, stream>>>(Af, Abt);
  k_packP<<<(NL * 2 * 64 * 64 + 255) / 256, 256, 0, stream>>>(preW, Pbt);

  k_gcnpre<<<NN / 4, 256, 0, stream>>>(x, Wg, dinv, bbh);
  k_gcnagg<<<NN / 4, 256, 0, stream>>>(bbh, off, ssrc, dinv, bg, hA);

  float* hin = hA;
  float* hout = hB;
  for (int l = 0; l < NL; ++l) {
    const float2* abl = (l == 0) ? nullptr : (ab + (l - 1) * 64);
    k_preM<<<(NN + 63) / 64, 256, 0, stream>>>(hin, abl, Pbt, preb, cb, bbh, l);
    k_agg<<<NN / 4, 256, 0, stream>>>(bbh, cb, off, ssrc, lgc, scal, agb, ampatt);
    k_gemm<<<(NN + 63) / 64, 256, 0, stream>>>(hin, abl, agb, ampatt,
                                               Abt + l * 13 * 4096, bias2 + l * 64, hout,
                                               bnsum + l * 1024);
    k_bnab<<<1, 64, 0, stream>>>(bnsum + l * 1024, gamma, beta, ab + l * 64, l);
    float* t = hin; hin = hout; hout = t;
  }
  k_gsum<<<NBUCK, 256, 0, stream>>>(hin, ab + 2 * 64, batch, gsum);
  k_mlp<<<1, 64, 0, stream>>>(gsum, W1, b1, W2, b2, out);
}

// Round 7
// 825.274 us; speedup vs baseline: 1.1344x; 1.1344x over previous
//
#include <hip/hip_runtime.h>
#include <math.h>

#define NN 100000
#define NE 1600000
#define NG 64
#define FF 50
#define NL 3
#define NBUCK ((NN + 255) / 256)   // 391

typedef short bf16x8 __attribute__((ext_vector_type(8)));
typedef float f32x4 __attribute__((ext_vector_type(4)));

__device__ __forceinline__ short f2bf(float f) {
  return __builtin_bit_cast(short, (__bf16)f);
}
__device__ __forceinline__ float bf2f(short s) {
  unsigned int u = ((unsigned int)(unsigned short)s) << 16;
  return __builtin_bit_cast(float, u);
}
__device__ __forceinline__ float2 unpk2(unsigned u) {
  float2 v;
  v.x = __builtin_bit_cast(float, u << 16);
  v.y = __builtin_bit_cast(float, u & 0xFFFF0000u);
  return v;
}
__device__ __forceinline__ unsigned pk2(float2 v) {
  return (unsigned)(unsigned short)f2bf(v.x) | ((unsigned)(unsigned short)f2bf(v.y) << 16);
}

// ---------------- degree ----------------
__global__ void k_deg(const int* __restrict__ dst, int* __restrict__ deg) {
  int e = blockIdx.x * blockDim.x + threadIdx.x;
  if (e < NE) atomicAdd(&deg[dst[e]], 1);
}

// ---------------- prefix scan ----------------
__global__ void k_scan1(const int* __restrict__ deg, int* __restrict__ off, int* __restrict__ parts) {
  __shared__ int sm[1024];
  int i = blockIdx.x * 1024 + threadIdx.x;
  int v = (i < NN) ? deg[i] : 0;
  sm[threadIdx.x] = v;
  __syncthreads();
  for (int ofs = 1; ofs < 1024; ofs <<= 1) {
    int t = (threadIdx.x >= ofs) ? sm[threadIdx.x - ofs] : 0;
    __syncthreads();
    sm[threadIdx.x] += t;
    __syncthreads();
  }
  if (i < NN) off[i] = sm[threadIdx.x] - v;
  if (threadIdx.x == 1023) parts[blockIdx.x] = sm[1023];
}

__global__ void k_scan2(int* __restrict__ parts, int nb) {
  __shared__ int sm[128];
  int v = (threadIdx.x < nb) ? parts[threadIdx.x] : 0;
  sm[threadIdx.x] = v;
  __syncthreads();
  for (int ofs = 1; ofs < 128; ofs <<= 1) {
    int t = (threadIdx.x >= ofs) ? sm[threadIdx.x - ofs] : 0;
    __syncthreads();
    sm[threadIdx.x] += t;
    __syncthreads();
  }
  if (threadIdx.x < nb) parts[threadIdx.x] = sm[threadIdx.x] - v;
}

__global__ void k_scan3(int* __restrict__ off, const int* __restrict__ parts, int* __restrict__ bcur) {
  int i = blockIdx.x * 256 + threadIdx.x;
  if (i < NN) {
    int v = off[i] + parts[i >> 10];
    off[i] = v;
    if ((i & 255) == 0) bcur[i >> 8] = v;
  }
  if (i == 0) off[NN] = NE;
}

// ---------------- node init ----------------
__global__ void k_nodeinit(const int* __restrict__ deg, float* __restrict__ dinv,
                           float* __restrict__ lgc, float* __restrict__ scal) {
  int i = blockIdx.x * 256 + threadIdx.x;
  float lp = 0.f;
  if (i < NN) {
    int d = deg[i];
    dinv[i] = rsqrtf((float)(d + 1));
    int dc = d > 1 ? d : 1;
    lgc[i] = log1pf((float)dc);
    lp = log1pf((float)d);
  }
  for (int o = 32; o > 0; o >>= 1) lp += __shfl_down(lp, o);
  __shared__ float red[4];
  int lane = threadIdx.x & 63, w = threadIdx.x >> 6;
  if (lane == 0) red[w] = lp;
  __syncthreads();
  if (threadIdx.x == 0) atomicAdd(scal, red[0] + red[1] + red[2] + red[3]);
}

// ---------------- phase A: bin edges ----------------
__global__ __launch_bounds__(256) void k_bucket(const int* __restrict__ src, const int* __restrict__ dst,
                                                int* __restrict__ bcur, unsigned* __restrict__ tmp) {
  __shared__ int hist[NBUCK];
  __shared__ int base[NBUCK];
  int t = threadIdx.x;
  for (int i = t; i < NBUCK; i += 256) hist[i] = 0;
  __syncthreads();
  int e0 = blockIdx.x * 4096;
  int myb[16], myrank[16];
  unsigned mypack[16];
#pragma unroll
  for (int i = 0; i < 16; ++i) {
    int e = e0 + i * 256 + t;
    if (e < NE) {
      int s = src[e], d = dst[e];
      int b = d >> 8;
      myb[i] = b;
      mypack[i] = ((unsigned)(d & 255) << 17) | (unsigned)s;
      myrank[i] = atomicAdd(&hist[b], 1);
    } else myb[i] = -1;
  }
  __syncthreads();
  for (int i = t; i < NBUCK; i += 256)
    base[i] = hist[i] ? atomicAdd(&bcur[i], hist[i]) : 0;
  __syncthreads();
#pragma unroll
  for (int i = 0; i < 16; ++i)
    if (myb[i] >= 0) tmp[base[myb[i]] + myrank[i]] = mypack[i];
}

// ---------------- phase B: bucket -> CSR ----------------
__global__ __launch_bounds__(256) void k_bsort(const int* __restrict__ off, const unsigned* __restrict__ tmp,
                                               int* __restrict__ ssrc) {
  int b = blockIdx.x;
  int n0 = b * 256;
  int nEnd = n0 + 256 < NN ? n0 + 256 : NN;
  __shared__ int cnt[256];
  __shared__ int nb[256];
  int t = threadIdx.x;
  cnt[t] = 0;
  if (n0 + t < nEnd) nb[t] = off[n0 + t];
  __syncthreads();
  int lo = off[n0], hiE = off[nEnd];
  for (int e = lo + t; e < hiE; e += 256) {
    unsigned p = tmp[e];
    int dloc = p >> 17;
    int s = (int)(p & 0x1FFFFu);
    int pos = nb[dloc] + atomicAdd(&cnt[dloc], 1);
    ssrc[pos] = s;
  }
}

// ---------------- fuse post_W @ lin_W ----------------
__global__ void k_fusew(const float* __restrict__ postW, const float* __restrict__ postb,
                        const float* __restrict__ linW, const float* __restrict__ linb,
                        float* __restrict__ A, float* __restrict__ bias2) {
  int wid = (blockIdx.x * blockDim.x + threadIdx.x) >> 6;
  int f = threadIdx.x & 63;
  if (wid >= 3 * 651) return;
  int l = wid / 651, r = wid % 651;
  int fc = f < FF ? f : FF - 1;
  const float* lw = linW + l * FF * FF;
  float acc = 0.f;
  if (r < 650) {
    const float* pw = postW + (l * 650 + r) * FF;
    for (int j = 0; j < FF; ++j) acc += pw[j] * lw[j * FF + fc];
    if (f < FF) A[(l * 650 + r) * FF + f] = acc;
  } else {
    const float* pb = postb + l * FF;
    for (int j = 0; j < FF; ++j) acc += pb[j] * lw[j * FF + fc];
    if (f < FF) bias2[l * 64 + f] = acc + linb[l * FF + f];
  }
}

// ---------------- pack A ----------------
__global__ void k_packA(const float* __restrict__ Af, short* __restrict__ Abt) {
  int t = blockIdx.x * 256 + threadIdx.x;
  if (t >= 3 * 13 * 64 * 64) return;
  int kk = t & 63;
  int f = (t >> 6) & 63;
  int lc = t >> 12;
  int c = lc % 13;
  int l = lc / 13;
  float v = 0.f;
  if (kk < FF && f < FF) v = Af[((size_t)(l * 650 + c * FF + kk)) * FF + f];
  Abt[t] = f2bf(v);
}

// ---------------- pack pre_W ----------------
__global__ void k_packP(const float* __restrict__ preW, short* __restrict__ Pbt) {
  int t = blockIdx.x * 256 + threadIdx.x;
  if (t >= NL * 2 * 64 * 64) return;
  int kk = t & 63;
  int f = (t >> 6) & 63;
  int ls = t >> 12;
  int s = ls & 1, l = ls >> 1;
  float v = 0.f;
  if (kk < FF && f < FF) v = preW[(size_t)(l * 100 + s * FF + kk) * FF + f];
  Pbt[t] = f2bf(v);
}

// ---------------- GCN pre ----------------
__global__ void k_gcnpre(const float* __restrict__ x, const float* __restrict__ Wg,
                         const float* __restrict__ dinv, short* __restrict__ pb) {
  int t = blockIdx.x * 256 + threadIdx.x;
  int n = t >> 6, f = t & 63;
  if (n >= NN) return;
  float v = 0.f;
  if (f < FF) v = (x[2 * n] * Wg[f] + x[2 * n + 1] * Wg[FF + f]) * dinv[n];
  pb[n * 64 + f] = f2bf(v);
}

// ---------------- GCN aggregation (packed: 2 edges x 2 features) ----------------
__global__ void k_gcnagg(const short* __restrict__ pb, const int* __restrict__ off,
                         const int* __restrict__ ssrc, const float* __restrict__ dinv,
                         const float* __restrict__ bg, float* __restrict__ h) {
  int wid = (blockIdx.x * blockDim.x + threadIdx.x) >> 6;
  int lane = threadIdx.x & 63;
  if (wid >= NN) return;
  int n = wid;
  int p = lane & 31;
  int hf = lane >> 5;
  float2 acc;
  {
    float2 sv = unpk2(*(const unsigned*)(pb + n * 64 + 2 * p));
    acc.x = hf ? 0.f : sv.x;
    acc.y = hf ? 0.f : sv.y;
  }
  int lo = off[n], hi = off[n + 1];
  for (int base = lo; base < hi; base += 64) {
    int rem = hi - base;
    int cnt = rem > 64 ? 64 : rem;
    int sidx = (base + lane < hi) ? ssrc[base + lane] : 0;
    int pairs = cnt >> 1;
    int j = 0;
    for (; j + 4 <= pairs; j += 4) {
#pragma unroll
      for (int i = 0; i < 4; ++i) {
        int s = __shfl(sidx, 2 * (j + i) + hf);
        float2 v = unpk2(*(const unsigned*)(pb + s * 64 + 2 * p));
        acc.x += v.x; acc.y += v.y;
      }
    }
    for (; j < pairs; ++j) {
      int s = __shfl(sidx, 2 * j + hf);
      float2 v = unpk2(*(const unsigned*)(pb + s * 64 + 2 * p));
      acc.x += v.x; acc.y += v.y;
    }
    if (cnt & 1) {
      int s = __shfl(sidx, cnt - 1);
      float2 v = unpk2(*(const unsigned*)(pb + s * 64 + 2 * p));
      if (hf == 0) { acc.x += v.x; acc.y += v.y; }
    }
  }
  acc.x += __shfl_xor(acc.x, 32);
  acc.y += __shfl_xor(acc.y, 32);
  if (lane < 32 && p < 25) {
    float dv = dinv[n];
    float2 bgp = *(const float2*)(bg + 2 * p);
    *(float2*)(h + n * FF + 2 * p) = make_float2(dv * acc.x + bgp.x, dv * acc.y + bgp.y);
  }
}

// ---------------- PNA pre (MFMA, barrier-free) ----------------
__global__ __launch_bounds__(256) void k_preM(const float* __restrict__ hin, const float2* __restrict__ ab,
                                              const short* __restrict__ Pbt, const float* __restrict__ preb,
                                              float* __restrict__ cb, short* __restrict__ bbh, int l) {
  __shared__ short Xs[64][72];
  int tid = threadIdx.x;
  int w = tid >> 6, lane = tid & 63;
  int q = lane >> 4, m16 = lane & 15;
  int n0 = blockIdx.x * 64 + w * 16;

  int nl = lane >> 2, ks = lane & 3;
  int n = n0 + nl;
  bool nv = n < NN;
  int row = w * 16 + nl;
  {
    const float* hrow = hin + (size_t)(nv ? n : 0) * FF;
    short tmp[16] __attribute__((aligned(16)));
#pragma unroll
    for (int j = 0; j < 16; j += 2) {
      int kk = ks * 16 + j;
      float2 v = {0.f, 0.f};
      if (nv && kk < FF) v = *(const float2*)(hrow + kk);
      if (ab) {
        float2 p0 = ab[kk], p1 = ab[kk + 1];
        v.x = fmaxf(fmaf(v.x, p0.x, p0.y), 0.f);
        v.y = fmaxf(fmaf(v.y, p1.x, p1.y), 0.f);
      }
      tmp[j] = f2bf(v.x); tmp[j + 1] = f2bf(v.y);
    }
    *(float4*)&Xs[row][ks * 16] = *(const float4*)&tmp[0];
    *(float4*)&Xs[row][ks * 16 + 8] = *(const float4*)&tmp[8];
  }
  const short* P0 = Pbt + l * 8192;
  f32x4 aT[4], aB2[4];
#pragma unroll
  for (int ft = 0; ft < 4; ++ft) {
    aT[ft] = (f32x4){0.f, 0.f, 0.f, 0.f};
    aB2[ft] = (f32x4){0.f, 0.f, 0.f, 0.f};
  }
#pragma unroll
  for (int hh = 0; hh < 2; ++hh) {
    bf16x8 a = *(const bf16x8*)&Xs[w * 16 + m16][hh * 32 + q * 8];
#pragma unroll
    for (int ft = 0; ft < 4; ++ft) {
      bf16x8 b0 = *(const bf16x8*)(P0 + ((ft * 16 + m16) << 6) + hh * 32 + q * 8);
      bf16x8 b1 = *(const bf16x8*)(P0 + 4096 + ((ft * 16 + m16) << 6) + hh * 32 + q * 8);
      aT[ft] = __builtin_amdgcn_mfma_f32_16x16x32_bf16(a, b0, aT[ft], 0, 0, 0);
      aB2[ft] = __builtin_amdgcn_mfma_f32_16x16x32_bf16(a, b1, aB2[ft], 0, 0, 0);
    }
  }
#pragma unroll
  for (int r = 0; r < 4; ++r) {
    int node = n0 + q * 4 + r;
    if (node >= NN) continue;
#pragma unroll
    for (int ft = 0; ft < 4; ++ft) {
      int col = ft * 16 + m16;
      if (col < FF) cb[node * FF + col] = aT[ft][r] + preb[l * FF + col];
      bbh[node * 64 + col] = f2bf(aB2[ft][r]);
    }
  }
}

// ---------------- PNA aggregation (packed: 2 edges x 2 features) ----------------
__global__ void k_agg(const short* __restrict__ bbh, const float* __restrict__ cb,
                      const int* __restrict__ off, const int* __restrict__ ssrc,
                      const float* __restrict__ lgc, const float* __restrict__ scal,
                      short* __restrict__ agb, float* __restrict__ ampatt) {
  int wid = (blockIdx.x * blockDim.x + threadIdx.x) >> 6;
  int lane = threadIdx.x & 63;
  if (wid >= NN) return;
  int n = wid;
  int p = lane & 31;
  int hf = lane >> 5;
  float2 S = {0.f, 0.f}, S2 = {0.f, 0.f};
  float2 MN = {INFINITY, INFINITY}, MX = {-INFINITY, -INFINITY};
  int lo = off[n], hi = off[n + 1];
  for (int base = lo; base < hi; base += 64) {
    int rem = hi - base;
    int cnt = rem > 64 ? 64 : rem;
    int sidx = (base + lane < hi) ? ssrc[base + lane] : 0;
    int pairs = cnt >> 1;
    int j = 0;
    for (; j + 4 <= pairs; j += 4) {
#pragma unroll
      for (int i = 0; i < 4; ++i) {
        int s = __shfl(sidx, 2 * (j + i) + hf);
        float2 v = unpk2(*(const unsigned*)(bbh + s * 64 + 2 * p));
        S.x += v.x; S.y += v.y;
        S2.x = fmaf(v.x, v.x, S2.x); S2.y = fmaf(v.y, v.y, S2.y);
        MN.x = fminf(MN.x, v.x); MN.y = fminf(MN.y, v.y);
        MX.x = fmaxf(MX.x, v.x); MX.y = fmaxf(MX.y, v.y);
      }
    }
    for (; j < pairs; ++j) {
      int s = __shfl(sidx, 2 * j + hf);
      float2 v = unpk2(*(const unsigned*)(bbh + s * 64 + 2 * p));
      S.x += v.x; S.y += v.y;
      S2.x = fmaf(v.x, v.x, S2.x); S2.y = fmaf(v.y, v.y, S2.y);
      MN.x = fminf(MN.x, v.x); MN.y = fminf(MN.y, v.y);
      MX.x = fmaxf(MX.x, v.x); MX.y = fmaxf(MX.y, v.y);
    }
    if (cnt & 1) {
      int s = __shfl(sidx, cnt - 1);
      float2 v = unpk2(*(const unsigned*)(bbh + s * 64 + 2 * p));
      if (hf == 0) {
        S.x += v.x; S.y += v.y;
        S2.x = fmaf(v.x, v.x, S2.x); S2.y = fmaf(v.y, v.y, S2.y);
        MN.x = fminf(MN.x, v.x); MN.y = fminf(MN.y, v.y);
        MX.x = fmaxf(MX.x, v.x); MX.y = fmaxf(MX.y, v.y);
      }
    }
  }
  S.x += __shfl_xor(S.x, 32);   S.y += __shfl_xor(S.y, 32);
  S2.x += __shfl_xor(S2.x, 32); S2.y += __shfl_xor(S2.y, 32);
  MN.x = fminf(MN.x, __shfl_xor(MN.x, 32)); MN.y = fminf(MN.y, __shfl_xor(MN.y, 32));
  MX.x = fmaxf(MX.x, __shfl_xor(MX.x, 32)); MX.y = fmaxf(MX.y, __shfl_xor(MX.y, 32));
  int d = hi - lo;
  bool valid = p < 25;
  float2 mean, mnv, mxv, stdv;
  if (d > 0) {
    float inv = 1.f / (float)d;
    float2 m = make_float2(S.x * inv, S.y * inv);
    float vx = S2.x * inv - m.x * m.x; vx = vx > 0.f ? vx : 0.f;
    float vy = S2.y * inv - m.y * m.y; vy = vy > 0.f ? vy : 0.f;
    stdv = make_float2(sqrtf(vx + 1e-5f), sqrtf(vy + 1e-5f));
    float2 c = valid ? *(const float2*)(cb + n * FF + 2 * p) : make_float2(0.f, 0.f);
    mean = make_float2(c.x + m.x, c.y + m.y);
    mnv = make_float2(c.x + MN.x, c.y + MN.y);
    mxv = make_float2(c.x + MX.x, c.y + MX.y);
  } else {
    mean = mnv = mxv = make_float2(0.f, 0.f);
    float sq = sqrtf(1e-5f);
    stdv = make_float2(sq, sq);
  }
  if (lane < 32) {
    unsigned* row32 = (unsigned*)(agb + (size_t)n * 256);
    row32[p]      = valid ? pk2(mean) : 0u;
    row32[32 + p] = valid ? pk2(mnv) : 0u;
    row32[64 + p] = valid ? pk2(mxv) : 0u;
    row32[96 + p] = valid ? pk2(stdv) : 0u;
  }
  if (lane == 0) {
    float avg = scal[0] * (1.f / NN);
    float lg = lgc[n];
    ampatt[2 * n] = lg / avg;
    ampatt[2 * n + 1] = avg / lg;
  }
}

// ---------------- post GEMM: A-frags in registers, B in LDS, prefetch pipeline ----------------
__global__ __launch_bounds__(256, 3) void k_gemm(const float* __restrict__ h, const float2* __restrict__ ab,
                                                 const short* __restrict__ agb, const float* __restrict__ ampatt,
                                                 const short* __restrict__ Abt, const float* __restrict__ bias2,
                                                 float* __restrict__ out, float* __restrict__ bnsumR) {
  __shared__ short Bs[3][64][72];   // 27.6 KB
  int tid = threadIdx.x;
  int w = tid >> 6, lane = tid & 63;
  int q = lane >> 4, m16 = lane & 15;
  int n0 = blockIdx.x * 64 + w * 16;

  // ---- A-fragments in registers: lane (q,m16) holds node n0+w*16+m16, k = hh*32+q*8.. ----
  int anode = n0 + m16;
  int nsafe = anode < NN ? anode : 0;
  bf16x8 afr[5][2];
  {
    const float* hrow = h + (size_t)nsafe * FF;
#pragma unroll
    for (int hh = 0; hh < 2; ++hh) {
      short tmp[8] __attribute__((aligned(16)));
#pragma unroll
      for (int j = 0; j < 8; ++j) {
        int kk = hh * 32 + q * 8 + j;
        float v = (kk < FF) ? hrow[kk] : 0.f;
        if (ab) { float2 pp = ab[kk]; v = fmaxf(fmaf(v, pp.x, pp.y), 0.f); }
        tmp[j] = f2bf(v);
      }
      afr[0][hh] = *(const bf16x8*)tmp;
    }
    const short* arow = agb + (size_t)nsafe * 256;
#pragma unroll
    for (int c = 1; c <= 4; ++c)
#pragma unroll
      for (int hh = 0; hh < 2; ++hh)
        afr[c][hh] = *(const bf16x8*)(arow + (c - 1) * 64 + hh * 32 + q * 8);
  }

  f32x4 acc[3][4];
#pragma unroll
  for (int s = 0; s < 3; ++s)
#pragma unroll
    for (int ft = 0; ft < 4; ++ft) acc[s][ft] = (f32x4){0.f, 0.f, 0.f, 0.f};

  // B staging roles
  int bf = tid >> 2;            // col 0..63
  int bko = (tid & 3) * 16;     // k offset
  float4 rg[3][2];
  // preload phase 0 (chunk 0 only)
  {
    const float4* g = (const float4*)(Abt + (bf << 6) + bko);
    rg[0][0] = g[0]; rg[0][1] = g[1];
  }
  for (int ph = 0; ph < 5; ++ph) {
    int nslice = (ph == 0) ? 1 : 3;
    if (ph) __syncthreads();                 // readers of previous phase done
    for (int s = 0; s < nslice; ++s) {
      *(float4*)&Bs[s][bf][bko] = rg[s][0];
      *(float4*)&Bs[s][bf][bko + 8] = rg[s][1];
    }
    __syncthreads();
    // prefetch next phase's B while doing MFMAs
    if (ph < 4) {
#pragma unroll
      for (int s = 0; s < 3; ++s) {
        int chunk = (ph + 1) + 4 * s;
        const float4* g = (const float4*)(Abt + (chunk << 12) + (bf << 6) + bko);
        rg[s][0] = g[0]; rg[s][1] = g[1];
      }
    }
    if (ph == 0) {
#pragma unroll
      for (int hh = 0; hh < 2; ++hh)
#pragma unroll
        for (int ft = 0; ft < 4; ++ft) {
          bf16x8 b = *(const bf16x8*)&Bs[0][ft * 16 + m16][hh * 32 + q * 8];
          acc[0][ft] = __builtin_amdgcn_mfma_f32_16x16x32_bf16(afr[0][hh], b, acc[0][ft], 0, 0, 0);
        }
    } else {
#pragma unroll
      for (int hh = 0; hh < 2; ++hh)
#pragma unroll
        for (int s = 0; s < 3; ++s)
#pragma unroll
          for (int ft = 0; ft < 4; ++ft) {
            bf16x8 b = *(const bf16x8*)&Bs[s][ft * 16 + m16][hh * 32 + q * 8];
            acc[s][ft] = __builtin_amdgcn_mfma_f32_16x16x32_bf16(afr[ph][hh], b, acc[s][ft], 0, 0, 0);
          }
    }
  }

  // ---- epilogue: out + BN partials (D: row=q*4+r node, col=ft*16+m16) ----
  float sacc[4] = {0.f, 0.f, 0.f, 0.f};
  float qacc[4] = {0.f, 0.f, 0.f, 0.f};
#pragma unroll
  for (int r = 0; r < 4; ++r) {
    int node = n0 + q * 4 + r;
    if (node >= NN) continue;
    float2 aa = *(const float2*)(ampatt + 2 * node);
#pragma unroll
    for (int ft = 0; ft < 4; ++ft) {
      int col = ft * 16 + m16;
      if (col >= FF) continue;
      float val = acc[0][ft][r] + aa.x * acc[1][ft][r] + aa.y * acc[2][ft][r] + bias2[col];
      out[node * FF + col] = val;
      sacc[ft] += val;
      qacc[ft] = fmaf(val, val, qacc[ft]);
    }
  }
#pragma unroll
  for (int ft = 0; ft < 4; ++ft) {
    sacc[ft] += __shfl_xor(sacc[ft], 16);
    sacc[ft] += __shfl_xor(sacc[ft], 32);
    qacc[ft] += __shfl_xor(qacc[ft], 16);
    qacc[ft] += __shfl_xor(qacc[ft], 32);
  }
  if (lane < 16) {
    float* bl = bnsumR + (blockIdx.x & 7) * 128;
#pragma unroll
    for (int ft = 0; ft < 4; ++ft) {
      int col = ft * 16 + lane;
      if (col < FF) {
        atomicAdd(&bl[col], sacc[ft]);
        atomicAdd(&bl[64 + col], qacc[ft]);
      }
    }
  }
}

// ---------------- BN coeffs from 8 replicas ----------------
__global__ void k_bnab(const float* __restrict__ bnsumR, const float* __restrict__ gamma,
                       const float* __restrict__ beta, float2* __restrict__ ab, int l) {
  int f = threadIdx.x;
  float a = 0.f, b = 0.f;
  if (f < FF) {
    float s = 0.f, q = 0.f;
    for (int r = 0; r < 8; ++r) { s += bnsumR[r * 128 + f]; q += bnsumR[r * 128 + 64 + f]; }
    float mu = s * (1.f / NN);
    float vq = q * (1.f / NN) - mu * mu;
    float rs = rsqrtf((vq > 0.f ? vq : 0.f) + 1e-5f);
    a = rs * gamma[l * FF + f];
    b = beta[l * FF + f] - mu * a;
  }
  ab[f] = make_float2(a, b);
}

// ---------------- graph partial sums (fused BN+ReLU of last layer) ----------------
__global__ void k_gsum(const float* __restrict__ h, const float2* __restrict__ ab,
                       const int* __restrict__ batch, float* __restrict__ gsum) {
  int w = threadIdx.x >> 6, lane = threadIdx.x & 63;
  int fc = lane < FF ? lane : FF - 1;
  bool act = lane < FF;
  float2 p = ab[fc];
  int n0 = blockIdx.x * 256 + w * 64;
  if (n0 >= NN) return;
  int nEnd = n0 + 64 < NN ? n0 + 64 : NN;
  float acc = 0.f;
  int gcur = batch[n0];
  for (int n = n0; n < nEnd; ++n) {
    int g = batch[n];
    if (g != gcur) {
      if (act) atomicAdd(&gsum[gcur * 64 + lane], acc);
      acc = 0.f; gcur = g;
    }
    float v = h[n * FF + fc];
    acc += fmaxf(fmaf(v, p.x, p.y), 0.f);
  }
  if (act) atomicAdd(&gsum[gcur * 64 + lane], acc);
}

// ---------------- final MLP ----------------
__global__ void k_mlp(const float* __restrict__ gsum, const float* __restrict__ W1,
                      const float* __restrict__ b1, const float* __restrict__ W2,
                      const float* __restrict__ b2, float* __restrict__ out) {
  int g = threadIdx.x;
  if (g >= NG) return;
  float gv[FF];
#pragma unroll
  for (int f = 0; f < FF; ++f) gv[f] = gsum[g * 64 + f];
  float r = b2[0];
  for (int j = 0; j < 25; ++j) {
    float a = b1[j];
#pragma unroll
    for (int f = 0; f < FF; ++f) a = fmaf(gv[f], W1[f * 25 + j], a);
    r += fmaxf(a, 0.f) * W2[j];
  }
  out[g] = r;
}

extern "C" void kernel_launch(void* const* d_in, const int* in_sizes, int n_in,
                              void* d_out, int out_size, void* d_ws, size_t ws_size,
                              hipStream_t stream) {
  const float* x     = (const float*)d_in[0];
  const int*   ei    = (const int*)d_in[1];
  const int*   src   = ei;
  const int*   dst   = ei + NE;
  const int*   batch = (const int*)d_in[2];
  const float* Wg    = (const float*)d_in[3];
  const float* bg    = (const float*)d_in[4];
  const float* preW  = (const float*)d_in[5];
  const float* preb  = (const float*)d_in[6];
  const float* postW = (const float*)d_in[7];
  const float* postb = (const float*)d_in[8];
  const float* linW  = (const float*)d_in[9];
  const float* linb  = (const float*)d_in[10];
  const float* gamma = (const float*)d_in[11];
  const float* beta  = (const float*)d_in[12];
  const float* W1    = (const float*)d_in[13];
  const float* b1    = (const float*)d_in[14];
  const float* W2    = (const float*)d_in[15];
  const float* b2    = (const float*)d_in[16];
  float* out = (float*)d_out;

  char* W = (char*)d_ws;
  int*    deg    = (int*)(W + 0);            // 400384
  int*    off    = (int*)(W + 400384);       // 400896
  int*    bcur   = (int*)(W + 801280);       // 2048
  int*    parts  = (int*)(W + 803328);       // 4096
  float*  dinv   = (float*)(W + 807424);     // 400384
  float*  lgc    = (float*)(W + 1207808);    // 400384
  float*  scal   = (float*)(W + 1608192);    // 512
  float*  bnsum  = (float*)(W + 1608704);    // 12288 (3 layers x 8 reps x 128 f)
  float2* ab     = (float2*)(W + 1620992);   // 1536
  float*  Af     = (float*)(W + 1622528);    // 390144
  float*  bias2  = (float*)(W + 2012672);    // 1024
  short*  Abt    = (short*)(W + 2013696);    // 319488
  short*  Pbt    = (short*)(W + 2333184);    // 49152
  unsigned* tmp  = (unsigned*)(W + 2382336); // 6400000
  int*    ssrc   = (int*)(W + 8782336);      // 6400000
  float*  hA     = (float*)(W + 15182336);   // 20000256
  float*  hB     = (float*)(W + 35182592);   // 20000256
  float*  cb     = (float*)(W + 55182848);   // 20000256
  short*  bbh    = (short*)(W + 75183104);   // 12800256
  short*  agb    = (short*)(W + 87983360);   // 51200256
  float*  ampatt = (float*)(W + 139183616);  // 800256
  float*  gsum   = (float*)(W + 139983872);  // 16384

  hipMemsetAsync(deg, 0, 400384, stream);
  hipMemsetAsync(scal, 0, 12800, stream);   // scal + bnsum
  hipMemsetAsync(gsum, 0, 16384, stream);

  k_deg<<<(NE + 255) / 256, 256, 0, stream>>>(dst, deg);
  k_scan1<<<98, 1024, 0, stream>>>(deg, off, parts);
  k_scan2<<<1, 128, 0, stream>>>(parts, 98);
  k_scan3<<<(NN + 255) / 256, 256, 0, stream>>>(off, parts, bcur);
  k_nodeinit<<<(NN + 255) / 256, 256, 0, stream>>>(deg, dinv, lgc, scal);
  k_bucket<<<(NE + 4095) / 4096, 256, 0, stream>>>(src, dst, bcur, tmp);
  k_bsort<<<NBUCK, 256, 0, stream>>>(off, tmp, ssrc);
  k_fusew<<<(3 * 651 + 3) / 4, 256, 0, stream>>>(postW, postb, linW, linb, Af, bias2);
  k_packA<<<(3 * 13 * 64 * 64 + 255) / 256, 256, 0, stream>>>(Af, Abt);
  k_packP<<<(NL * 2 * 64 * 64 + 255) / 256, 256, 0, stream>>>(preW, Pbt);

  k_gcnpre<<<NN / 4, 256, 0, stream>>>(x, Wg, dinv, bbh);
  k_gcnagg<<<NN / 4, 256, 0, stream>>>(bbh, off, ssrc, dinv, bg, hA);

  float* hin = hA;
  float* hout = hB;
  for (int l = 0; l < NL; ++l) {
    const float2* abl = (l == 0) ? nullptr : (ab + (l - 1) * 64);
    k_preM<<<(NN + 63) / 64, 256, 0, stream>>>(hin, abl, Pbt, preb, cb, bbh, l);
    k_agg<<<NN / 4, 256, 0, stream>>>(bbh, cb, off, ssrc, lgc, scal, agb, ampatt);
    k_gemm<<<(NN + 63) / 64, 256, 0, stream>>>(hin, abl, agb, ampatt,
                                               Abt + l * 13 * 4096, bias2 + l * 64, hout,
                                               bnsum + l * 1024);
    k_bnab<<<1, 64, 0, stream>>>(bnsum + l * 1024, gamma, beta, ab + l * 64, l);
    float* t = hin; hin = hout; hout = t;
  }
  k_gsum<<<NBUCK, 256, 0, stream>>>(hin, ab + 2 * 64, batch, gsum);
  k_mlp<<<1, 64, 0, stream>>>(gsum, W1, b1, W2, b2, out);
}

// Round 8
// 783.808 us; speedup vs baseline: 1.1944x; 1.0529x over previous
//
#include <hip/hip_runtime.h>
#include <math.h>

#define NN 100000
#define NE 1600000
#define NG 64
#define FF 50
#define NL 3
#define NBUCK ((NN + 255) / 256)   // 391

typedef short bf16x8 __attribute__((ext_vector_type(8)));
typedef float f32x4 __attribute__((ext_vector_type(4)));

__device__ __forceinline__ short f2bf(float f) {
  return __builtin_bit_cast(short, (__bf16)f);
}
__device__ __forceinline__ float bf2f(short s) {
  unsigned int u = ((unsigned int)(unsigned short)s) << 16;
  return __builtin_bit_cast(float, u);
}
__device__ __forceinline__ float2 unpk2(unsigned u) {
  float2 v;
  v.x = __builtin_bit_cast(float, u << 16);
  v.y = __builtin_bit_cast(float, u & 0xFFFF0000u);
  return v;
}
__device__ __forceinline__ unsigned pk2(float2 v) {
  return (unsigned)(unsigned short)f2bf(v.x) | ((unsigned)(unsigned short)f2bf(v.y) << 16);
}

// load a 16B bf16 fragment and apply BN+ReLU per element (ab = per-feature a,b)
__device__ __forceinline__ bf16x8 ldfrag_bn(const short* base, const float2* __restrict__ ab, int kbase) {
  bf16x8 raw = *(const bf16x8*)base;
  unsigned u[4];
  __builtin_memcpy(u, &raw, 16);
  short t[8] __attribute__((aligned(16)));
#pragma unroll
  for (int i = 0; i < 4; ++i) {
    float2 v = unpk2(u[i]);
    float2 a0 = ab[kbase + 2 * i], a1 = ab[kbase + 2 * i + 1];
    v.x = fmaxf(fmaf(v.x, a0.x, a0.y), 0.f);
    v.y = fmaxf(fmaf(v.y, a1.x, a1.y), 0.f);
    ((unsigned*)t)[i] = pk2(v);
  }
  bf16x8 r;
  __builtin_memcpy(&r, t, 16);
  return r;
}

// ---------------- degree ----------------
__global__ void k_deg(const int* __restrict__ dst, int* __restrict__ deg) {
  int e = blockIdx.x * blockDim.x + threadIdx.x;
  if (e < NE) atomicAdd(&deg[dst[e]], 1);
}

// ---------------- prefix scan ----------------
__global__ void k_scan1(const int* __restrict__ deg, int* __restrict__ off, int* __restrict__ parts) {
  __shared__ int sm[1024];
  int i = blockIdx.x * 1024 + threadIdx.x;
  int v = (i < NN) ? deg[i] : 0;
  sm[threadIdx.x] = v;
  __syncthreads();
  for (int ofs = 1; ofs < 1024; ofs <<= 1) {
    int t = (threadIdx.x >= ofs) ? sm[threadIdx.x - ofs] : 0;
    __syncthreads();
    sm[threadIdx.x] += t;
    __syncthreads();
  }
  if (i < NN) off[i] = sm[threadIdx.x] - v;
  if (threadIdx.x == 1023) parts[blockIdx.x] = sm[1023];
}

__global__ void k_scan2(int* __restrict__ parts, int nb) {
  __shared__ int sm[128];
  int v = (threadIdx.x < nb) ? parts[threadIdx.x] : 0;
  sm[threadIdx.x] = v;
  __syncthreads();
  for (int ofs = 1; ofs < 128; ofs <<= 1) {
    int t = (threadIdx.x >= ofs) ? sm[threadIdx.x - ofs] : 0;
    __syncthreads();
    sm[threadIdx.x] += t;
    __syncthreads();
  }
  if (threadIdx.x < nb) parts[threadIdx.x] = sm[threadIdx.x] - v;
}

__global__ void k_scan3(int* __restrict__ off, const int* __restrict__ parts, int* __restrict__ bcur) {
  int i = blockIdx.x * 256 + threadIdx.x;
  if (i < NN) {
    int v = off[i] + parts[i >> 10];
    off[i] = v;
    if ((i & 255) == 0) bcur[i >> 8] = v;
  }
  if (i == 0) off[NN] = NE;
}

// ---------------- node init ----------------
__global__ void k_nodeinit(const int* __restrict__ deg, float* __restrict__ dinv,
                           float* __restrict__ lgc, float* __restrict__ scal) {
  int i = blockIdx.x * 256 + threadIdx.x;
  float lp = 0.f;
  if (i < NN) {
    int d = deg[i];
    dinv[i] = rsqrtf((float)(d + 1));
    int dc = d > 1 ? d : 1;
    lgc[i] = log1pf((float)dc);
    lp = log1pf((float)d);
  }
  for (int o = 32; o > 0; o >>= 1) lp += __shfl_down(lp, o);
  __shared__ float red[4];
  int lane = threadIdx.x & 63, w = threadIdx.x >> 6;
  if (lane == 0) red[w] = lp;
  __syncthreads();
  if (threadIdx.x == 0) atomicAdd(scal, red[0] + red[1] + red[2] + red[3]);
}

// ---------------- phase A: bin edges ----------------
__global__ __launch_bounds__(256) void k_bucket(const int* __restrict__ src, const int* __restrict__ dst,
                                                int* __restrict__ bcur, unsigned* __restrict__ tmp) {
  __shared__ int hist[NBUCK];
  __shared__ int base[NBUCK];
  int t = threadIdx.x;
  for (int i = t; i < NBUCK; i += 256) hist[i] = 0;
  __syncthreads();
  int e0 = blockIdx.x * 4096;
  int myb[16], myrank[16];
  unsigned mypack[16];
#pragma unroll
  for (int i = 0; i < 16; ++i) {
    int e = e0 + i * 256 + t;
    if (e < NE) {
      int s = src[e], d = dst[e];
      int b = d >> 8;
      myb[i] = b;
      mypack[i] = ((unsigned)(d & 255) << 17) | (unsigned)s;
      myrank[i] = atomicAdd(&hist[b], 1);
    } else myb[i] = -1;
  }
  __syncthreads();
  for (int i = t; i < NBUCK; i += 256)
    base[i] = hist[i] ? atomicAdd(&bcur[i], hist[i]) : 0;
  __syncthreads();
#pragma unroll
  for (int i = 0; i < 16; ++i)
    if (myb[i] >= 0) tmp[base[myb[i]] + myrank[i]] = mypack[i];
}

// ---------------- phase B: bucket -> CSR ----------------
__global__ __launch_bounds__(256) void k_bsort(const int* __restrict__ off, const unsigned* __restrict__ tmp,
                                               int* __restrict__ ssrc) {
  int b = blockIdx.x;
  int n0 = b * 256;
  int nEnd = n0 + 256 < NN ? n0 + 256 : NN;
  __shared__ int cnt[256];
  __shared__ int nb[256];
  int t = threadIdx.x;
  cnt[t] = 0;
  if (n0 + t < nEnd) nb[t] = off[n0 + t];
  __syncthreads();
  int lo = off[n0], hiE = off[nEnd];
  for (int e = lo + t; e < hiE; e += 256) {
    unsigned p = tmp[e];
    int dloc = p >> 17;
    int s = (int)(p & 0x1FFFFu);
    int pos = nb[dloc] + atomicAdd(&cnt[dloc], 1);
    ssrc[pos] = s;
  }
}

// ---------------- fuse post_W @ lin_W ----------------
__global__ void k_fusew(const float* __restrict__ postW, const float* __restrict__ postb,
                        const float* __restrict__ linW, const float* __restrict__ linb,
                        float* __restrict__ A, float* __restrict__ bias2) {
  int wid = (blockIdx.x * blockDim.x + threadIdx.x) >> 6;
  int f = threadIdx.x & 63;
  if (wid >= 3 * 651) return;
  int l = wid / 651, r = wid % 651;
  int fc = f < FF ? f : FF - 1;
  const float* lw = linW + l * FF * FF;
  float acc = 0.f;
  if (r < 650) {
    const float* pw = postW + (l * 650 + r) * FF;
    for (int j = 0; j < FF; ++j) acc += pw[j] * lw[j * FF + fc];
    if (f < FF) A[(l * 650 + r) * FF + f] = acc;
  } else {
    const float* pb = postb + l * FF;
    for (int j = 0; j < FF; ++j) acc += pb[j] * lw[j * FF + fc];
    bias2[l * 64 + f] = (f < FF) ? (acc + linb[l * FF + f]) : 0.f;
  }
}

// ---------------- pack A ----------------
__global__ void k_packA(const float* __restrict__ Af, short* __restrict__ Abt) {
  int t = blockIdx.x * 256 + threadIdx.x;
  if (t >= 3 * 13 * 64 * 64) return;
  int kk = t & 63;
  int f = (t >> 6) & 63;
  int lc = t >> 12;
  int c = lc % 13;
  int l = lc / 13;
  float v = 0.f;
  if (kk < FF && f < FF) v = Af[((size_t)(l * 650 + c * FF + kk)) * FF + f];
  Abt[t] = f2bf(v);
}

// ---------------- pack pre_W ----------------
__global__ void k_packP(const float* __restrict__ preW, short* __restrict__ Pbt) {
  int t = blockIdx.x * 256 + threadIdx.x;
  if (t >= NL * 2 * 64 * 64) return;
  int kk = t & 63;
  int f = (t >> 6) & 63;
  int ls = t >> 12;
  int s = ls & 1, l = ls >> 1;
  float v = 0.f;
  if (kk < FF && f < FF) v = preW[(size_t)(l * 100 + s * FF + kk) * FF + f];
  Pbt[t] = f2bf(v);
}

// ---------------- GCN pre ----------------
__global__ void k_gcnpre(const float* __restrict__ x, const float* __restrict__ Wg,
                         const float* __restrict__ dinv, short* __restrict__ pb) {
  int t = blockIdx.x * 256 + threadIdx.x;
  int n = t >> 6, f = t & 63;
  if (n >= NN) return;
  float v = 0.f;
  if (f < FF) v = (x[2 * n] * Wg[f] + x[2 * n + 1] * Wg[FF + f]) * dinv[n];
  pb[n * 64 + f] = f2bf(v);
}

// ---------------- GCN aggregation (packed: 2 edges x 2 features), bf16 h out ----------------
__global__ void k_gcnagg(const short* __restrict__ pb, const int* __restrict__ off,
                         const int* __restrict__ ssrc, const float* __restrict__ dinv,
                         const float* __restrict__ bg, short* __restrict__ hb) {
  int wid = (blockIdx.x * blockDim.x + threadIdx.x) >> 6;
  int lane = threadIdx.x & 63;
  if (wid >= NN) return;
  int n = wid;
  int p = lane & 31;
  int hf = lane >> 5;
  float2 acc;
  {
    float2 sv = unpk2(*(const unsigned*)(pb + n * 64 + 2 * p));
    acc.x = hf ? 0.f : sv.x;
    acc.y = hf ? 0.f : sv.y;
  }
  int lo = off[n], hi = off[n + 1];
  for (int base = lo; base < hi; base += 64) {
    int rem = hi - base;
    int cnt = rem > 64 ? 64 : rem;
    int sidx = (base + lane < hi) ? ssrc[base + lane] : 0;
    int pairs = cnt >> 1;
    int j = 0;
    for (; j + 4 <= pairs; j += 4) {
#pragma unroll
      for (int i = 0; i < 4; ++i) {
        int s = __shfl(sidx, 2 * (j + i) + hf);
        float2 v = unpk2(*(const unsigned*)(pb + s * 64 + 2 * p));
        acc.x += v.x; acc.y += v.y;
      }
    }
    for (; j < pairs; ++j) {
      int s = __shfl(sidx, 2 * j + hf);
      float2 v = unpk2(*(const unsigned*)(pb + s * 64 + 2 * p));
      acc.x += v.x; acc.y += v.y;
    }
    if (cnt & 1) {
      int s = __shfl(sidx, cnt - 1);
      float2 v = unpk2(*(const unsigned*)(pb + s * 64 + 2 * p));
      if (hf == 0) { acc.x += v.x; acc.y += v.y; }
    }
  }
  acc.x += __shfl_xor(acc.x, 32);
  acc.y += __shfl_xor(acc.y, 32);
  if (lane < 32) {
    float2 o = make_float2(0.f, 0.f);
    if (p < 25) {
      float dv = dinv[n];
      float2 bgp = *(const float2*)(bg + 2 * p);
      o = make_float2(dv * acc.x + bgp.x, dv * acc.y + bgp.y);
    }
    ((unsigned*)(hb + n * 64))[p] = pk2(o);
  }
}

// ---------------- PNA pre (MFMA, LDS-free, bf16 h in, bf16 cb/bb out) ----------------
__global__ __launch_bounds__(256) void k_preM(const short* __restrict__ hin, const float2* __restrict__ ab,
                                              const short* __restrict__ Pbt, const float* __restrict__ preb,
                                              short* __restrict__ cbh, short* __restrict__ bbh, int l) {
  int tid = threadIdx.x;
  int w = tid >> 6, lane = tid & 63;
  int q = lane >> 4, m16 = lane & 15;
  int n0 = blockIdx.x * 64 + w * 16;
  int anode = n0 + m16;
  int nsafe = anode < NN ? anode : 0;
  bf16x8 afr[2];
#pragma unroll
  for (int hh = 0; hh < 2; ++hh) {
    const short* srcp = hin + (size_t)nsafe * 64 + hh * 32 + q * 8;
    afr[hh] = ab ? ldfrag_bn(srcp, ab, hh * 32 + q * 8) : *(const bf16x8*)srcp;
  }
  const short* P0 = Pbt + l * 8192;
  f32x4 aT[4], aB2[4];
#pragma unroll
  for (int ft = 0; ft < 4; ++ft) {
    aT[ft] = (f32x4){0.f, 0.f, 0.f, 0.f};
    aB2[ft] = (f32x4){0.f, 0.f, 0.f, 0.f};
  }
#pragma unroll
  for (int hh = 0; hh < 2; ++hh) {
#pragma unroll
    for (int ft = 0; ft < 4; ++ft) {
      bf16x8 b0 = *(const bf16x8*)(P0 + ((ft * 16 + m16) << 6) + hh * 32 + q * 8);
      bf16x8 b1 = *(const bf16x8*)(P0 + 4096 + ((ft * 16 + m16) << 6) + hh * 32 + q * 8);
      aT[ft] = __builtin_amdgcn_mfma_f32_16x16x32_bf16(afr[hh], b0, aT[ft], 0, 0, 0);
      aB2[ft] = __builtin_amdgcn_mfma_f32_16x16x32_bf16(afr[hh], b1, aB2[ft], 0, 0, 0);
    }
  }
#pragma unroll
  for (int r = 0; r < 4; ++r) {
    int node = n0 + q * 4 + r;
    if (node >= NN) continue;
#pragma unroll
    for (int ft = 0; ft < 4; ++ft) {
      int col = ft * 16 + m16;
      cbh[node * 64 + col] = (col < FF) ? f2bf(aT[ft][r] + preb[l * FF + col]) : 0;
      bbh[node * 64 + col] = f2bf(aB2[ft][r]);
    }
  }
}

// ---------------- PNA aggregation (packed: 2 edges x 2 features) ----------------
__global__ void k_agg(const short* __restrict__ bbh, const short* __restrict__ cbh,
                      const int* __restrict__ off, const int* __restrict__ ssrc,
                      const float* __restrict__ lgc, const float* __restrict__ scal,
                      short* __restrict__ agb, float* __restrict__ ampatt) {
  int wid = (blockIdx.x * blockDim.x + threadIdx.x) >> 6;
  int lane = threadIdx.x & 63;
  if (wid >= NN) return;
  int n = wid;
  int p = lane & 31;
  int hf = lane >> 5;
  float2 S = {0.f, 0.f}, S2 = {0.f, 0.f};
  float2 MN = {INFINITY, INFINITY}, MX = {-INFINITY, -INFINITY};
  int lo = off[n], hi = off[n + 1];
  for (int base = lo; base < hi; base += 64) {
    int rem = hi - base;
    int cnt = rem > 64 ? 64 : rem;
    int sidx = (base + lane < hi) ? ssrc[base + lane] : 0;
    int pairs = cnt >> 1;
    int j = 0;
    for (; j + 4 <= pairs; j += 4) {
#pragma unroll
      for (int i = 0; i < 4; ++i) {
        int s = __shfl(sidx, 2 * (j + i) + hf);
        float2 v = unpk2(*(const unsigned*)(bbh + s * 64 + 2 * p));
        S.x += v.x; S.y += v.y;
        S2.x = fmaf(v.x, v.x, S2.x); S2.y = fmaf(v.y, v.y, S2.y);
        MN.x = fminf(MN.x, v.x); MN.y = fminf(MN.y, v.y);
        MX.x = fmaxf(MX.x, v.x); MX.y = fmaxf(MX.y, v.y);
      }
    }
    for (; j < pairs; ++j) {
      int s = __shfl(sidx, 2 * j + hf);
      float2 v = unpk2(*(const unsigned*)(bbh + s * 64 + 2 * p));
      S.x += v.x; S.y += v.y;
      S2.x = fmaf(v.x, v.x, S2.x); S2.y = fmaf(v.y, v.y, S2.y);
      MN.x = fminf(MN.x, v.x); MN.y = fminf(MN.y, v.y);
      MX.x = fmaxf(MX.x, v.x); MX.y = fmaxf(MX.y, v.y);
    }
    if (cnt & 1) {
      int s = __shfl(sidx, cnt - 1);
      float2 v = unpk2(*(const unsigned*)(bbh + s * 64 + 2 * p));
      if (hf == 0) {
        S.x += v.x; S.y += v.y;
        S2.x = fmaf(v.x, v.x, S2.x); S2.y = fmaf(v.y, v.y, S2.y);
        MN.x = fminf(MN.x, v.x); MN.y = fminf(MN.y, v.y);
        MX.x = fmaxf(MX.x, v.x); MX.y = fmaxf(MX.y, v.y);
      }
    }
  }
  S.x += __shfl_xor(S.x, 32);   S.y += __shfl_xor(S.y, 32);
  S2.x += __shfl_xor(S2.x, 32); S2.y += __shfl_xor(S2.y, 32);
  MN.x = fminf(MN.x, __shfl_xor(MN.x, 32)); MN.y = fminf(MN.y, __shfl_xor(MN.y, 32));
  MX.x = fmaxf(MX.x, __shfl_xor(MX.x, 32)); MX.y = fmaxf(MX.y, __shfl_xor(MX.y, 32));
  int d = hi - lo;
  bool valid = p < 25;
  float2 mean, mnv, mxv, stdv;
  if (d > 0) {
    float inv = 1.f / (float)d;
    float2 m = make_float2(S.x * inv, S.y * inv);
    float vx = S2.x * inv - m.x * m.x; vx = vx > 0.f ? vx : 0.f;
    float vy = S2.y * inv - m.y * m.y; vy = vy > 0.f ? vy : 0.f;
    stdv = make_float2(sqrtf(vx + 1e-5f), sqrtf(vy + 1e-5f));
    float2 c = valid ? unpk2(((const unsigned*)(cbh + n * 64))[p]) : make_float2(0.f, 0.f);
    mean = make_float2(c.x + m.x, c.y + m.y);
    mnv = make_float2(c.x + MN.x, c.y + MN.y);
    mxv = make_float2(c.x + MX.x, c.y + MX.y);
  } else {
    mean = mnv = mxv = make_float2(0.f, 0.f);
    float sq = sqrtf(1e-5f);
    stdv = make_float2(sq, sq);
  }
  if (lane < 32) {
    unsigned* row32 = (unsigned*)(agb + (size_t)n * 256);
    row32[p]      = valid ? pk2(mean) : 0u;
    row32[32 + p] = valid ? pk2(mnv) : 0u;
    row32[64 + p] = valid ? pk2(mxv) : 0u;
    row32[96 + p] = valid ? pk2(stdv) : 0u;
  }
  if (lane == 0) {
    float avg = scal[0] * (1.f / NN);
    float lg = lgc[n];
    ampatt[2 * n] = lg / avg;
    ampatt[2 * n + 1] = avg / lg;
  }
}

// ---------------- post GEMM: A-frags in registers, B in LDS, prefetch; bf16 in/out ----------------
__global__ __launch_bounds__(256, 3) void k_gemm(const short* __restrict__ h, const float2* __restrict__ ab,
                                                 const short* __restrict__ agb, const float* __restrict__ ampatt,
                                                 const short* __restrict__ Abt, const float* __restrict__ bias2,
                                                 short* __restrict__ hout, float* __restrict__ bnsumR) {
  __shared__ short Bs[3][64][72];   // 27.6 KB
  int tid = threadIdx.x;
  int w = tid >> 6, lane = tid & 63;
  int q = lane >> 4, m16 = lane & 15;
  int n0 = blockIdx.x * 64 + w * 16;

  // A-fragments in registers
  int anode = n0 + m16;
  int nsafe = anode < NN ? anode : 0;
  bf16x8 afr[5][2];
  {
#pragma unroll
    for (int hh = 0; hh < 2; ++hh) {
      const short* srcp = h + (size_t)nsafe * 64 + hh * 32 + q * 8;
      afr[0][hh] = ab ? ldfrag_bn(srcp, ab, hh * 32 + q * 8) : *(const bf16x8*)srcp;
    }
    const short* arow = agb + (size_t)nsafe * 256;
#pragma unroll
    for (int c = 1; c <= 4; ++c)
#pragma unroll
      for (int hh = 0; hh < 2; ++hh)
        afr[c][hh] = *(const bf16x8*)(arow + (c - 1) * 64 + hh * 32 + q * 8);
  }

  f32x4 acc[3][4];
#pragma unroll
  for (int s = 0; s < 3; ++s)
#pragma unroll
    for (int ft = 0; ft < 4; ++ft) acc[s][ft] = (f32x4){0.f, 0.f, 0.f, 0.f};

  // B staging roles
  int bf = tid >> 2;
  int bko = (tid & 3) * 16;
  float4 rg[3][2];
  {
    const float4* g = (const float4*)(Abt + (bf << 6) + bko);
    rg[0][0] = g[0]; rg[0][1] = g[1];
  }
  for (int ph = 0; ph < 5; ++ph) {
    int nslice = (ph == 0) ? 1 : 3;
    if (ph) __syncthreads();
    for (int s = 0; s < nslice; ++s) {
      *(float4*)&Bs[s][bf][bko] = rg[s][0];
      *(float4*)&Bs[s][bf][bko + 8] = rg[s][1];
    }
    __syncthreads();
    if (ph < 4) {
#pragma unroll
      for (int s = 0; s < 3; ++s) {
        int chunk = (ph + 1) + 4 * s;
        const float4* g = (const float4*)(Abt + (chunk << 12) + (bf << 6) + bko);
        rg[s][0] = g[0]; rg[s][1] = g[1];
      }
    }
    if (ph == 0) {
#pragma unroll
      for (int hh = 0; hh < 2; ++hh)
#pragma unroll
        for (int ft = 0; ft < 4; ++ft) {
          bf16x8 b = *(const bf16x8*)&Bs[0][ft * 16 + m16][hh * 32 + q * 8];
          acc[0][ft] = __builtin_amdgcn_mfma_f32_16x16x32_bf16(afr[0][hh], b, acc[0][ft], 0, 0, 0);
        }
    } else {
#pragma unroll
      for (int hh = 0; hh < 2; ++hh)
#pragma unroll
        for (int s = 0; s < 3; ++s)
#pragma unroll
          for (int ft = 0; ft < 4; ++ft) {
            bf16x8 b = *(const bf16x8*)&Bs[s][ft * 16 + m16][hh * 32 + q * 8];
            acc[s][ft] = __builtin_amdgcn_mfma_f32_16x16x32_bf16(afr[ph][hh], b, acc[s][ft], 0, 0, 0);
          }
    }
  }

  // epilogue: bf16 store (pad cols zeroed) + BN partials in fp32
  float sacc[4] = {0.f, 0.f, 0.f, 0.f};
  float qacc[4] = {0.f, 0.f, 0.f, 0.f};
#pragma unroll
  for (int r = 0; r < 4; ++r) {
    int node = n0 + q * 4 + r;
    if (node >= NN) continue;
    float2 aa = *(const float2*)(ampatt + 2 * node);
#pragma unroll
    for (int ft = 0; ft < 4; ++ft) {
      int col = ft * 16 + m16;
      float val = 0.f;
      if (col < FF) {
        val = acc[0][ft][r] + aa.x * acc[1][ft][r] + aa.y * acc[2][ft][r] + bias2[col];
        sacc[ft] += val;
        qacc[ft] = fmaf(val, val, qacc[ft]);
      }
      hout[node * 64 + col] = f2bf(val);
    }
  }
#pragma unroll
  for (int ft = 0; ft < 4; ++ft) {
    sacc[ft] += __shfl_xor(sacc[ft], 16);
    sacc[ft] += __shfl_xor(sacc[ft], 32);
    qacc[ft] += __shfl_xor(qacc[ft], 16);
    qacc[ft] += __shfl_xor(qacc[ft], 32);
  }
  if (lane < 16) {
    float* bl = bnsumR + (blockIdx.x & 7) * 128;
#pragma unroll
    for (int ft = 0; ft < 4; ++ft) {
      int col = ft * 16 + lane;
      if (col < FF) {
        atomicAdd(&bl[col], sacc[ft]);
        atomicAdd(&bl[64 + col], qacc[ft]);
      }
    }
  }
}

// ---------------- BN coeffs from 8 replicas ----------------
__global__ void k_bnab(const float* __restrict__ bnsumR, const float* __restrict__ gamma,
                       const float* __restrict__ beta, float2* __restrict__ ab, int l) {
  int f = threadIdx.x;
  float a = 0.f, b = 0.f;
  if (f < FF) {
    float s = 0.f, q = 0.f;
    for (int r = 0; r < 8; ++r) { s += bnsumR[r * 128 + f]; q += bnsumR[r * 128 + 64 + f]; }
    float mu = s * (1.f / NN);
    float vq = q * (1.f / NN) - mu * mu;
    float rs = rsqrtf((vq > 0.f ? vq : 0.f) + 1e-5f);
    a = rs * gamma[l * FF + f];
    b = beta[l * FF + f] - mu * a;
  }
  ab[f] = make_float2(a, b);
}

// ---------------- graph partial sums (fused BN+ReLU of last layer, bf16 h) ----------------
__global__ void k_gsum(const short* __restrict__ h, const float2* __restrict__ ab,
                       const int* __restrict__ batch, float* __restrict__ gsum) {
  int w = threadIdx.x >> 6, lane = threadIdx.x & 63;
  int fc = lane < FF ? lane : FF - 1;
  bool act = lane < FF;
  float2 p = ab[fc];
  int n0 = blockIdx.x * 256 + w * 64;
  if (n0 >= NN) return;
  int nEnd = n0 + 64 < NN ? n0 + 64 : NN;
  float acc = 0.f;
  int gcur = batch[n0];
  for (int n = n0; n < nEnd; ++n) {
    int g = batch[n];
    if (g != gcur) {
      if (act) atomicAdd(&gsum[gcur * 64 + lane], acc);
      acc = 0.f; gcur = g;
    }
    float v = bf2f(h[n * 64 + fc]);
    acc += fmaxf(fmaf(v, p.x, p.y), 0.f);
  }
  if (act) atomicAdd(&gsum[gcur * 64 + lane], acc);
}

// ---------------- final MLP ----------------
__global__ void k_mlp(const float* __restrict__ gsum, const float* __restrict__ W1,
                      const float* __restrict__ b1, const float* __restrict__ W2,
                      const float* __restrict__ b2, float* __restrict__ out) {
  int g = threadIdx.x;
  if (g >= NG) return;
  float gv[FF];
#pragma unroll
  for (int f = 0; f < FF; ++f) gv[f] = gsum[g * 64 + f];
  float r = b2[0];
  for (int j = 0; j < 25; ++j) {
    float a = b1[j];
#pragma unroll
    for (int f = 0; f < FF; ++f) a = fmaf(gv[f], W1[f * 25 + j], a);
    r += fmaxf(a, 0.f) * W2[j];
  }
  out[g] = r;
}

extern "C" void kernel_launch(void* const* d_in, const int* in_sizes, int n_in,
                              void* d_out, int out_size, void* d_ws, size_t ws_size,
                              hipStream_t stream) {
  const float* x     = (const float*)d_in[0];
  const int*   ei    = (const int*)d_in[1];
  const int*   src   = ei;
  const int*   dst   = ei + NE;
  const int*   batch = (const int*)d_in[2];
  const float* Wg    = (const float*)d_in[3];
  const float* bg    = (const float*)d_in[4];
  const float* preW  = (const float*)d_in[5];
  const float* preb  = (const float*)d_in[6];
  const float* postW = (const float*)d_in[7];
  const float* postb = (const float*)d_in[8];
  const float* linW  = (const float*)d_in[9];
  const float* linb  = (const float*)d_in[10];
  const float* gamma = (const float*)d_in[11];
  const float* beta  = (const float*)d_in[12];
  const float* W1    = (const float*)d_in[13];
  const float* b1    = (const float*)d_in[14];
  const float* W2    = (const float*)d_in[15];
  const float* b2    = (const float*)d_in[16];
  float* out = (float*)d_out;

  char* W = (char*)d_ws;
  int*    deg    = (int*)(W + 0);            // 400384
  int*    off    = (int*)(W + 400384);       // 400896
  int*    bcur   = (int*)(W + 801280);       // 2048
  int*    parts  = (int*)(W + 803328);       // 4096
  float*  dinv   = (float*)(W + 807424);     // 400384
  float*  lgc    = (float*)(W + 1207808);    // 400384
  float*  scal   = (float*)(W + 1608192);    // 512
  float*  bnsum  = (float*)(W + 1608704);    // 12288
  float2* ab     = (float2*)(W + 1620992);   // 1536
  float*  Af     = (float*)(W + 1622528);    // 390144
  float*  bias2  = (float*)(W + 2012672);    // 1024
  short*  Abt    = (short*)(W + 2013696);    // 319488
  short*  Pbt    = (short*)(W + 2333184);    // 49152
  unsigned* tmp  = (unsigned*)(W + 2382336); // 6400000
  int*    ssrc   = (int*)(W + 8782336);      // 6400000
  short*  hA     = (short*)(W + 15182336);   // 12800256 (bf16 [node][64])
  short*  hB     = (short*)(W + 27982592);   // 12800256
  short*  cbh    = (short*)(W + 40782848);   // 12800256 (bf16 [node][64])
  short*  bbh    = (short*)(W + 53583104);   // 12800256 (bf16 [node][64]; also GCN p)
  short*  agb    = (short*)(W + 66383360);   // 51200256 (bf16 [node][256])
  float*  ampatt = (float*)(W + 117583616);  // 800256
  float*  gsum   = (float*)(W + 118383872);  // 16384   (total ~118.4 MB)

  hipMemsetAsync(deg, 0, 400384, stream);
  hipMemsetAsync(scal, 0, 12800, stream);   // scal + bnsum
  hipMemsetAsync(gsum, 0, 16384, stream);

  k_deg<<<(NE + 255) / 256, 256, 0, stream>>>(dst, deg);
  k_scan1<<<98, 1024, 0, stream>>>(deg, off, parts);
  k_scan2<<<1, 128, 0, stream>>>(parts, 98);
  k_scan3<<<(NN + 255) / 256, 256, 0, stream>>>(off, parts, bcur);
  k_nodeinit<<<(NN + 255) / 256, 256, 0, stream>>>(deg, dinv, lgc, scal);
  k_bucket<<<(NE + 4095) / 4096, 256, 0, stream>>>(src, dst, bcur, tmp);
  k_bsort<<<NBUCK, 256, 0, stream>>>(off, tmp, ssrc);
  k_fusew<<<(3 * 651 + 3) / 4, 256, 0, stream>>>(postW, postb, linW, linb, Af, bias2);
  k_packA<<<(3 * 13 * 64 * 64 + 255) / 256, 256, 0, stream>>>(Af, Abt);
  k_packP<<<(NL * 2 * 64 * 64 + 255) / 256, 256, 0, stream>>>(preW, Pbt);

  k_gcnpre<<<NN / 4, 256, 0, stream>>>(x, Wg, dinv, bbh);
  k_gcnagg<<<NN / 4, 256, 0, stream>>>(bbh, off, ssrc, dinv, bg, hA);

  short* hin = hA;
  short* hout = hB;
  for (int l = 0; l < NL; ++l) {
    const float2* abl = (l == 0) ? nullptr : (ab + (l - 1) * 64);
    k_preM<<<(NN + 63) / 64, 256, 0, stream>>>(hin, abl, Pbt, preb, cbh, bbh, l);
    k_agg<<<NN / 4, 256, 0, stream>>>(bbh, cbh, off, ssrc, lgc, scal, agb, ampatt);
    k_gemm<<<(NN + 63) / 64, 256, 0, stream>>>(hin, abl, agb, ampatt,
                                               Abt + l * 13 * 4096, bias2 + l * 64, hout,
                                               bnsum + l * 1024);
    k_bnab<<<1, 64, 0, stream>>>(bnsum + l * 1024, gamma, beta, ab + l * 64, l);
    short* t = hin; hin = hout; hout = t;
  }
  k_gsum<<<NBUCK, 256, 0, stream>>>(hin, ab + 2 * 64, batch, gsum);
  k_mlp<<<1, 64, 0, stream>>>(gsum, W1, b1, W2, b2, out);
}